// Round 3
// baseline (628.258 us; speedup 1.0000x reference)
//
#include <hip/hip_runtime.h>

#define INC 256
#define HD 128
#define ZD 64
#define SBS 256

// ---------------- graph preprocessing ----------------

__global__ void k_count(const int* __restrict__ dst, int* __restrict__ cnt, int E) {
    int i = blockIdx.x * blockDim.x + threadIdx.x;
    if (i < E) atomicAdd(&cnt[dst[i]], 1);
}

__global__ void k_dinv(const int* __restrict__ cnt, float* __restrict__ dinv, int n) {
    int i = blockIdx.x * blockDim.x + threadIdx.x;
    if (i < n) dinv[i] = rsqrtf((float)(cnt[i] + 1));  // +1 self-loop
}

__global__ void k_scan1(const int* __restrict__ cnt, int* __restrict__ part, int n) {
    __shared__ int s[SBS];
    int i = blockIdx.x * SBS + threadIdx.x;
    s[threadIdx.x] = (i < n) ? cnt[i] : 0;
    __syncthreads();
    for (int o = SBS / 2; o > 0; o >>= 1) {
        if (threadIdx.x < o) s[threadIdx.x] += s[threadIdx.x + o];
        __syncthreads();
    }
    if (threadIdx.x == 0) part[blockIdx.x] = s[0];
}

__global__ void k_scan2(int* __restrict__ part, int nb) {
    __shared__ int s[SBS];
    int t = threadIdx.x;
    int v = (t < nb) ? part[t] : 0;
    s[t] = v;
    __syncthreads();
    for (int o = 1; o < SBS; o <<= 1) {
        int x = (t >= o) ? s[t - o] : 0;
        __syncthreads();
        s[t] += x;
        __syncthreads();
    }
    if (t < nb) part[t] = s[t] - v;  // exclusive
}

__global__ void k_scan3(const int* __restrict__ cnt, const int* __restrict__ part,
                        int* __restrict__ rowstart, int n) {
    __shared__ int s[SBS];
    int t = threadIdx.x;
    int i = blockIdx.x * SBS + t;
    int v = (i < n) ? cnt[i] : 0;
    s[t] = v;
    __syncthreads();
    for (int o = 1; o < SBS; o <<= 1) {
        int x = (t >= o) ? s[t - o] : 0;
        __syncthreads();
        s[t] += x;
        __syncthreads();
    }
    if (i < n) rowstart[i] = part[blockIdx.x] + s[t] - v;
}

__global__ void k_scatter(const int* __restrict__ src, const int* __restrict__ dst,
                          const int* __restrict__ rowstart, int* __restrict__ cursor,
                          int* __restrict__ csr, int E) {
    int i = blockIdx.x * blockDim.x + threadIdx.x;
    if (i < E) {
        int d = dst[i];
        int p = rowstart[d] + atomicAdd(&cursor[d], 1);
        csr[p] = src[i];
    }
}

__global__ void k_wcat(const float* __restrict__ wmu, const float* __restrict__ wls,
                       float* __restrict__ wcat) {
    int i = blockIdx.x * blockDim.x + threadIdx.x;  // HD*HD
    int k = i >> 7, j = i & 127;
    wcat[i] = (j < ZD) ? wmu[k * ZD + j] : wls[k * ZD + (j - ZD)];
}

// ---------------- dense GEMM: Y[n,128] = X[n,K] @ W[K,128] ----------------
// block = 256 threads, 16 rows per block; thread = (tx: 4 cols, ty: 2 rows)

template <int K>
__global__ __launch_bounds__(256) void k_gemm(const float* __restrict__ X,
                                              const float* __restrict__ W,
                                              float* __restrict__ Y) {
    __shared__ float xs[16][K];
    const int row0 = blockIdx.x * 16;
    const int tx = threadIdx.x & 31, ty = threadIdx.x >> 5;

    const float4* xv = reinterpret_cast<const float4*>(X + (size_t)row0 * K);
    float4* sv = reinterpret_cast<float4*>(&xs[0][0]);
#pragma unroll
    for (int i = threadIdx.x; i < 16 * K / 4; i += 256) sv[i] = xv[i];
    __syncthreads();

    float acc0[4] = {0.f, 0.f, 0.f, 0.f};
    float acc1[4] = {0.f, 0.f, 0.f, 0.f};
    const int r0 = ty * 2;
#pragma unroll 4
    for (int k = 0; k < K; k++) {
        float4 w = *reinterpret_cast<const float4*>(W + (size_t)k * HD + tx * 4);
        float x0 = xs[r0][k], x1 = xs[r0 + 1][k];
        acc0[0] += x0 * w.x; acc0[1] += x0 * w.y; acc0[2] += x0 * w.z; acc0[3] += x0 * w.w;
        acc1[0] += x1 * w.x; acc1[1] += x1 * w.y; acc1[2] += x1 * w.z; acc1[3] += x1 * w.w;
    }
    float4 o0 = make_float4(acc0[0], acc0[1], acc0[2], acc0[3]);
    float4 o1 = make_float4(acc1[0], acc1[1], acc1[2], acc1[3]);
    *reinterpret_cast<float4*>(Y + (size_t)(row0 + r0) * HD + tx * 4) = o0;
    *reinterpret_cast<float4*>(Y + (size_t)(row0 + r0 + 1) * HD + tx * 4) = o1;
}

// ---------------- aggregation: out[d] = dd*(sum_e dinv[s]*in[s] + dd*in[d]) + b ----
// one wave per dst row; lane handles cols 2*lane, 2*lane+1 (float2)
// 4-way unrolled gather for memory-level parallelism (gathers are L2/L3 hits,
// ~200-400 cy; 4 outstanding row-loads per lane hides more latency)

template <int RELU, int SPLIT>
__global__ __launch_bounds__(256) void k_agg(const float* __restrict__ in,
                                             const int* __restrict__ csr,
                                             const int* __restrict__ rowstart,
                                             const int* __restrict__ cnt,
                                             const float* __restrict__ dinv,
                                             const float* __restrict__ b0,
                                             const float* __restrict__ b1,
                                             float* __restrict__ out0,
                                             float* __restrict__ out1, int n) {
    const int wid = threadIdx.x >> 6;
    const int lane = threadIdx.x & 63;
    const int d = blockIdx.x * 4 + wid;
    if (d >= n) return;

    const float dd = dinv[d];
    const float2* in2 = reinterpret_cast<const float2*>(in);
    float2 selfv = in2[(size_t)d * 64 + lane];
    float ax = dd * selfv.x, ay = dd * selfv.y;

    const int base = rowstart[d];
    const int m = cnt[d];
    int k = 0;
    for (; k + 3 < m; k += 4) {
        int s0 = csr[base + k];
        int s1 = csr[base + k + 1];
        int s2 = csr[base + k + 2];
        int s3 = csr[base + k + 3];
        float ds0 = dinv[s0], ds1 = dinv[s1], ds2 = dinv[s2], ds3 = dinv[s3];
        float2 v0 = in2[(size_t)s0 * 64 + lane];
        float2 v1 = in2[(size_t)s1 * 64 + lane];
        float2 v2 = in2[(size_t)s2 * 64 + lane];
        float2 v3 = in2[(size_t)s3 * 64 + lane];
        ax += ds0 * v0.x + ds1 * v1.x + ds2 * v2.x + ds3 * v3.x;
        ay += ds0 * v0.y + ds1 * v1.y + ds2 * v2.y + ds3 * v3.y;
    }
    for (; k < m; k++) {
        int s0 = csr[base + k];
        float ds0 = dinv[s0];
        float2 v0 = in2[(size_t)s0 * 64 + lane];
        ax += ds0 * v0.x;
        ay += ds0 * v0.y;
    }
    ax *= dd; ay *= dd;

    if (!SPLIT) {
        float2 b = reinterpret_cast<const float2*>(b0)[lane];
        ax += b.x; ay += b.y;
        if (RELU) { ax = fmaxf(ax, 0.f); ay = fmaxf(ay, 0.f); }
        reinterpret_cast<float2*>(out0)[(size_t)d * 64 + lane] = make_float2(ax, ay);
    } else {
        if (lane < 32) {
            float2 b = reinterpret_cast<const float2*>(b0)[lane];
            reinterpret_cast<float2*>(out0)[(size_t)d * 32 + lane] = make_float2(ax + b.x, ay + b.y);
        } else {
            float2 b = reinterpret_cast<const float2*>(b1)[lane - 32];
            reinterpret_cast<float2*>(out1)[(size_t)d * 32 + (lane - 32)] = make_float2(ax + b.x, ay + b.y);
        }
    }
}

// ---------------- launch ----------------

extern "C" void kernel_launch(void* const* d_in, const int* in_sizes, int n_in,
                              void* d_out, int out_size, void* d_ws, size_t ws_size,
                              hipStream_t stream) {
    const float* x    = (const float*)d_in[0];
    const float* W_h  = (const float*)d_in[1];
    const float* b_h  = (const float*)d_in[2];
    const float* W_mu = (const float*)d_in[3];
    const float* b_mu = (const float*)d_in[4];
    const float* W_ls = (const float*)d_in[5];
    const float* b_ls = (const float*)d_in[6];
    const int*   ei   = (const int*)d_in[7];

    const int E = in_sizes[7] / 2;
    const int n = in_sizes[0] / INC;  // 50000
    const int* src = ei;
    const int* dst = ei + E;
    float* out = (float*)d_out;

    // workspace carve (256B aligned)
    char* p = (char*)d_ws;
    auto carve = [&](size_t bytes) {
        void* r = (void*)p;
        p += (bytes + 255) & ~(size_t)255;
        return r;
    };
    float* xw1      = (float*)carve((size_t)n * HD * 4);  // also reused as hw
    float* h        = (float*)carve((size_t)n * HD * 4);
    float* wcat     = (float*)carve((size_t)HD * HD * 4);
    float* dinv     = (float*)carve((size_t)n * 4);
    int*   cnt      = (int*)carve((size_t)n * 4);
    int*   rowstart = (int*)carve((size_t)n * 4);
    int*   cursor   = (int*)carve((size_t)n * 4);
    int*   part     = (int*)carve((size_t)SBS * 4);
    int*   csr      = (int*)carve((size_t)E * 4);
    float* hw = xw1;

    hipMemsetAsync(cnt, 0, (size_t)n * 4, stream);
    hipMemsetAsync(cursor, 0, (size_t)n * 4, stream);

    const int nb = (n + SBS - 1) / SBS;
    k_count<<<(E + 255) / 256, 256, 0, stream>>>(dst, cnt, E);
    k_dinv<<<(n + 255) / 256, 256, 0, stream>>>(cnt, dinv, n);
    k_scan1<<<nb, SBS, 0, stream>>>(cnt, part, n);
    k_scan2<<<1, SBS, 0, stream>>>(part, nb);
    k_scan3<<<nb, SBS, 0, stream>>>(cnt, part, rowstart, n);
    k_scatter<<<(E + 255) / 256, 256, 0, stream>>>(src, dst, rowstart, cursor, csr, E);
    k_wcat<<<(HD * HD) / 256, 256, 0, stream>>>(W_mu, W_ls, wcat);

    k_gemm<INC><<<n / 16, 256, 0, stream>>>(x, W_h, xw1);
    k_agg<1, 0><<<(n + 3) / 4, 256, 0, stream>>>(xw1, csr, rowstart, cnt, dinv,
                                                 b_h, nullptr, h, nullptr, n);
    k_gemm<HD><<<n / 16, 256, 0, stream>>>(h, wcat, hw);
    k_agg<0, 1><<<(n + 3) / 4, 256, 0, stream>>>(hw, csr, rowstart, cnt, dinv,
                                                 b_mu, b_ls, out, out + (size_t)n * ZD, n);
}

// Round 4
// 430.273 us; speedup vs baseline: 1.4601x; 1.4601x over previous
//
#include <hip/hip_runtime.h>

#define INC 256
#define HD 128
#define ZD 64
#define SBS 256

typedef __attribute__((ext_vector_type(8))) short bf16x8;
typedef __attribute__((ext_vector_type(4))) float f32x4;

static __device__ __forceinline__ unsigned short f2b(float f) {
    unsigned u = __builtin_bit_cast(unsigned, f);
    unsigned r = (u + 0x7fffu + ((u >> 16) & 1u)) >> 16;  // RNE
    return (unsigned short)r;
}
static __device__ __forceinline__ float b_lo(unsigned u) {  // low ushort -> f32
    return __builtin_bit_cast(float, u << 16);
}
static __device__ __forceinline__ float b_hi(unsigned u) {  // high ushort -> f32
    return __builtin_bit_cast(float, u & 0xffff0000u);
}

// ---------------- graph preprocessing ----------------

__global__ void k_count(const int* __restrict__ dst, int* __restrict__ cnt, int E) {
    int i = blockIdx.x * blockDim.x + threadIdx.x;
    if (i < E) atomicAdd(&cnt[dst[i]], 1);
}

__global__ void k_dinv(const int* __restrict__ cnt, float* __restrict__ dinv, int n) {
    int i = blockIdx.x * blockDim.x + threadIdx.x;
    if (i < n) dinv[i] = rsqrtf((float)(cnt[i] + 1));  // +1 self-loop
}

__global__ void k_scan1(const int* __restrict__ cnt, int* __restrict__ part, int n) {
    __shared__ int s[SBS];
    int i = blockIdx.x * SBS + threadIdx.x;
    s[threadIdx.x] = (i < n) ? cnt[i] : 0;
    __syncthreads();
    for (int o = SBS / 2; o > 0; o >>= 1) {
        if (threadIdx.x < o) s[threadIdx.x] += s[threadIdx.x + o];
        __syncthreads();
    }
    if (threadIdx.x == 0) part[blockIdx.x] = s[0];
}

__global__ void k_scan2(int* __restrict__ part, int nb) {
    __shared__ int s[SBS];
    int t = threadIdx.x;
    int v = (t < nb) ? part[t] : 0;
    s[t] = v;
    __syncthreads();
    for (int o = 1; o < SBS; o <<= 1) {
        int x = (t >= o) ? s[t - o] : 0;
        __syncthreads();
        s[t] += x;
        __syncthreads();
    }
    if (t < nb) part[t] = s[t] - v;  // exclusive
}

__global__ void k_scan3(const int* __restrict__ cnt, const int* __restrict__ part,
                        int* __restrict__ rowstart, int n) {
    __shared__ int s[SBS];
    int t = threadIdx.x;
    int i = blockIdx.x * SBS + t;
    int v = (i < n) ? cnt[i] : 0;
    s[t] = v;
    __syncthreads();
    for (int o = 1; o < SBS; o <<= 1) {
        int x = (t >= o) ? s[t - o] : 0;
        __syncthreads();
        s[t] += x;
        __syncthreads();
    }
    if (i < n) rowstart[i] = part[blockIdx.x] + s[t] - v;
}

__global__ void k_scatter(const int* __restrict__ src, const int* __restrict__ dst,
                          const int* __restrict__ rowstart, int* __restrict__ cursor,
                          int* __restrict__ csr, int E) {
    int i = blockIdx.x * blockDim.x + threadIdx.x;
    if (i < E) {
        int d = dst[i];
        int p = rowstart[d] + atomicAdd(&cursor[d], 1);
        csr[p] = src[i];
    }
}

// ---------------- bf16 cast: x[f32] -> xb[bf16], 4 elems/thread ----------------

__global__ void k_cast(const float4* __restrict__ x, uint2* __restrict__ xb, int n4) {
    int i = blockIdx.x * blockDim.x + threadIdx.x;
    if (i < n4) {
        float4 v = x[i];
        uint2 o;
        o.x = (unsigned)f2b(v.x) | ((unsigned)f2b(v.y) << 16);
        o.y = (unsigned)f2b(v.z) | ((unsigned)f2b(v.w) << 16);
        xb[i] = o;
    }
}

// ---------------- W pack: [K][128] f32 -> MFMA B-fragment-major bf16 ----------
// frag (s,c): lane l, elem j  <-  W[s*32 + (l>>4)*8 + j][c*16 + (l&15)]
// packed idx = ((s*8 + c)*64 + l)*8 + j

template <int K, int SPLITB>
__global__ void k_pack(const float* __restrict__ Wa, const float* __restrict__ Wb,
                       unsigned short* __restrict__ Wp) {
    int idx = blockIdx.x * 256 + threadIdx.x;  // < K*128
    int j = idx & 7, lane = (idx >> 3) & 63, c = (idx >> 9) & 7, s = idx >> 12;
    int k = s * 32 + (lane >> 4) * 8 + j;
    int col = c * 16 + (lane & 15);
    float v;
    if (!SPLITB) v = Wa[k * 128 + col];
    else v = (col < 64) ? Wa[k * 64 + col] : Wb[k * 64 + (col - 64)];
    Wp[idx] = f2b(v);
}

// ---------------- MFMA GEMM: Y[n,128](bf16) = Xb[n,K](bf16) @ Wp ----------------
// 4 waves/block, wave = 16 rows x 128 cols; LDS-free; per 32-k step:
// 1 A-frag global load + 8 B-frag loads (L1-hot packed W) + 8 MFMAs.

template <int K>
__global__ __launch_bounds__(256) void k_mgemm(const unsigned short* __restrict__ Xb,
                                               const unsigned short* __restrict__ Wp,
                                               unsigned short* __restrict__ Y, int n) {
    const int lane = threadIdx.x & 63;
    const int w = threadIdx.x >> 6;
    const int rowbase = blockIdx.x * 64 + w * 16;
    int arow = rowbase + (lane & 15);
    if (arow >= n) arow = n - 1;  // clamp; stores are guarded
    const int kgrp = lane >> 4;

    f32x4 acc[8] = {};
#pragma unroll
    for (int s = 0; s < K / 32; s++) {
        bf16x8 a = *reinterpret_cast<const bf16x8*>(Xb + (size_t)arow * K + s * 32 + kgrp * 8);
        const bf16x8* bp = reinterpret_cast<const bf16x8*>(Wp) + ((size_t)s * 8 * 64 + lane);
#pragma unroll
        for (int c = 0; c < 8; c++) {
            bf16x8 b = bp[c * 64];
            acc[c] = __builtin_amdgcn_mfma_f32_16x16x32_bf16(a, b, acc[c], 0, 0, 0);
        }
    }
    const int r0 = rowbase + (lane >> 4) * 4;
    const int col = lane & 15;
#pragma unroll
    for (int c = 0; c < 8; c++) {
#pragma unroll
        for (int r = 0; r < 4; r++) {
            int rr = r0 + r;
            if (rr < n) Y[(size_t)rr * 128 + c * 16 + col] = f2b(acc[c][r]);
        }
    }
}

// ---------------- aggregation: out[d] = dd*(sum_e dinv[s]*in[s] + dd*in[d]) + b ----
// in is bf16 [n][128] viewed as uint [n][64]; lane covers cols {2l, 2l+1}.
// f32 accumulate; 4-way unrolled gather for MLP.

template <int RELU, int SPLIT>
__global__ __launch_bounds__(256) void k_agg(const unsigned* __restrict__ in,
                                             const int* __restrict__ csr,
                                             const int* __restrict__ rowstart,
                                             const int* __restrict__ cnt,
                                             const float* __restrict__ dinv,
                                             const float* __restrict__ b0,
                                             const float* __restrict__ b1,
                                             void* __restrict__ out0v,
                                             void* __restrict__ out1v, int n) {
    const int wid = threadIdx.x >> 6;
    const int lane = threadIdx.x & 63;
    const int d = blockIdx.x * 4 + wid;
    if (d >= n) return;

    const float dd = dinv[d];
    unsigned su = in[(size_t)d * 64 + lane];
    float ax = dd * b_lo(su), ay = dd * b_hi(su);

    const int base = rowstart[d];
    const int m = cnt[d];
    int k = 0;
    for (; k + 3 < m; k += 4) {
        int s0 = csr[base + k];
        int s1 = csr[base + k + 1];
        int s2 = csr[base + k + 2];
        int s3 = csr[base + k + 3];
        float ds0 = dinv[s0], ds1 = dinv[s1], ds2 = dinv[s2], ds3 = dinv[s3];
        unsigned u0 = in[(size_t)s0 * 64 + lane];
        unsigned u1 = in[(size_t)s1 * 64 + lane];
        unsigned u2 = in[(size_t)s2 * 64 + lane];
        unsigned u3 = in[(size_t)s3 * 64 + lane];
        ax += ds0 * b_lo(u0) + ds1 * b_lo(u1) + ds2 * b_lo(u2) + ds3 * b_lo(u3);
        ay += ds0 * b_hi(u0) + ds1 * b_hi(u1) + ds2 * b_hi(u2) + ds3 * b_hi(u3);
    }
    for (; k < m; k++) {
        int s0 = csr[base + k];
        float ds0 = dinv[s0];
        unsigned u0 = in[(size_t)s0 * 64 + lane];
        ax += ds0 * b_lo(u0);
        ay += ds0 * b_hi(u0);
    }
    ax *= dd; ay *= dd;

    if (!SPLIT) {
        float2 b = reinterpret_cast<const float2*>(b0)[lane];
        ax += b.x; ay += b.y;
        if (RELU) { ax = fmaxf(ax, 0.f); ay = fmaxf(ay, 0.f); }
        ((unsigned*)out0v)[(size_t)d * 64 + lane] =
            (unsigned)f2b(ax) | ((unsigned)f2b(ay) << 16);
    } else {
        if (lane < 32) {
            float2 b = reinterpret_cast<const float2*>(b0)[lane];
            reinterpret_cast<float2*>(out0v)[(size_t)d * 32 + lane] =
                make_float2(ax + b.x, ay + b.y);
        } else {
            float2 b = reinterpret_cast<const float2*>(b1)[lane - 32];
            reinterpret_cast<float2*>(out1v)[(size_t)d * 32 + (lane - 32)] =
                make_float2(ax + b.x, ay + b.y);
        }
    }
}

// ---------------- launch ----------------

extern "C" void kernel_launch(void* const* d_in, const int* in_sizes, int n_in,
                              void* d_out, int out_size, void* d_ws, size_t ws_size,
                              hipStream_t stream) {
    const float* x    = (const float*)d_in[0];
    const float* W_h  = (const float*)d_in[1];
    const float* b_h  = (const float*)d_in[2];
    const float* W_mu = (const float*)d_in[3];
    const float* b_mu = (const float*)d_in[4];
    const float* W_ls = (const float*)d_in[5];
    const float* b_ls = (const float*)d_in[6];
    const int*   ei   = (const int*)d_in[7];

    const int E = in_sizes[7] / 2;
    const int n = in_sizes[0] / INC;  // 50000
    const int* src = ei;
    const int* dst = ei + E;
    float* out = (float*)d_out;

    // workspace carve (256B aligned)
    char* p = (char*)d_ws;
    auto carve = [&](size_t bytes) {
        void* r = (void*)p;
        p += (bytes + 255) & ~(size_t)255;
        return r;
    };
    unsigned short* xb   = (unsigned short*)carve((size_t)n * INC * 2);  // x in bf16
    unsigned short* xw   = (unsigned short*)carve((size_t)n * HD * 2);   // gemm1 out / gemm2 out (reused)
    unsigned short* h    = (unsigned short*)carve((size_t)n * HD * 2);   // agg1 out
    unsigned short* wp1  = (unsigned short*)carve((size_t)INC * HD * 2); // packed W_h
    unsigned short* wp2  = (unsigned short*)carve((size_t)HD * HD * 2);  // packed [W_mu|W_ls]
    float* dinv     = (float*)carve((size_t)n * 4);
    int*   cnt      = (int*)carve((size_t)n * 4);
    int*   rowstart = (int*)carve((size_t)n * 4);
    int*   cursor   = (int*)carve((size_t)n * 4);
    int*   part     = (int*)carve((size_t)SBS * 4);
    int*   csr      = (int*)carve((size_t)E * 4);
    unsigned short* hw = xw;  // gemm2 output reuses xw

    hipMemsetAsync(cnt, 0, (size_t)n * 4, stream);
    hipMemsetAsync(cursor, 0, (size_t)n * 4, stream);

    const int nb = (n + SBS - 1) / SBS;
    k_count<<<(E + 255) / 256, 256, 0, stream>>>(dst, cnt, E);
    k_dinv<<<(n + 255) / 256, 256, 0, stream>>>(cnt, dinv, n);
    k_scan1<<<nb, SBS, 0, stream>>>(cnt, part, n);
    k_scan2<<<1, SBS, 0, stream>>>(part, nb);
    k_scan3<<<nb, SBS, 0, stream>>>(cnt, part, rowstart, n);
    k_scatter<<<(E + 255) / 256, 256, 0, stream>>>(src, dst, rowstart, cursor, csr, E);

    const int n4 = n * INC / 4;
    k_cast<<<(n4 + 255) / 256, 256, 0, stream>>>((const float4*)x, (uint2*)xb, n4);
    k_pack<INC, 0><<<INC * HD / 256, 256, 0, stream>>>(W_h, nullptr, wp1);
    k_pack<HD, 1><<<HD * HD / 256, 256, 0, stream>>>(W_mu, W_ls, wp2);

    k_mgemm<INC><<<(n + 63) / 64, 256, 0, stream>>>(xb, wp1, xw, n);
    k_agg<1, 0><<<(n + 3) / 4, 256, 0, stream>>>((const unsigned*)xw, csr, rowstart, cnt,
                                                 dinv, b_h, nullptr, h, nullptr, n);
    k_mgemm<HD><<<(n + 63) / 64, 256, 0, stream>>>(h, wp2, hw, n);
    k_agg<0, 1><<<(n + 3) / 4, 256, 0, stream>>>((const unsigned*)hw, csr, rowstart, cnt,
                                                 dinv, b_mu, b_ls, out, out + (size_t)n * ZD, n);
}